// Round 1
// baseline (1287.745 us; speedup 1.0000x reference)
//
#include <hip/hip_runtime.h>

#define AS1 __attribute__((address_space(1)))
#define AS3 __attribute__((address_space(3)))

typedef __bf16 bf16;
typedef __bf16 bf16x8 __attribute__((ext_vector_type(8)));
typedef __bf16 bf16x4v __attribute__((ext_vector_type(4)));
typedef float  f32x4  __attribute__((ext_vector_type(4)));

#define MFMA16(a,b,c) __builtin_amdgcn_mfma_f32_16x16x32_bf16((a),(b),(c),0,0,0)

static __device__ __forceinline__ void gll16(const bf16* src, bf16* lds) {
  __builtin_amdgcn_global_load_lds((const AS1 void*)src, (AS3 void*)lds, 16, 0, 0);
}

// ---------------- Kernel 0: weights fp32 -> bf16 ----------------
__global__ void convw_k(const float* __restrict__ s, bf16* __restrict__ d) {
  int i = (blockIdx.x * 256 + threadIdx.x) * 4;
  float4 v = *(const float4*)(s + i);
  bf16x4v o;
  o[0] = (bf16)v.x; o[1] = (bf16)v.y; o[2] = (bf16)v.z; o[3] = (bf16)v.w;
  *(bf16x4v*)(d + i) = o;
}

// ------------- Kernel 1: transpose+convert feat [B,C,4096] -> [B,4096,C] bf16 -------------
__global__ void tconv_k(const float* __restrict__ f0, const float* __restrict__ f1,
                        bf16* __restrict__ xq, bf16* __restrict__ xkv) {
  const int z = blockIdx.z;
  const int b = z & 7;
  const float* src = (z < 8) ? f0 : f1;
  bf16* dst = (z < 8) ? xq : xkv;
  const int n0 = blockIdx.x * 32, c0 = blockIdx.y * 32;
  __shared__ float tile[32][33];
  const int tx = threadIdx.x, ty = threadIdx.y;
  const size_t base = (size_t)b * 512 * 4096;
#pragma unroll
  for (int i = 0; i < 4; i++) {
    int c = ty + i * 8;
    tile[c][tx] = src[base + (size_t)(c0 + c) * 4096 + n0 + tx];
  }
  __syncthreads();
  const size_t ob = (size_t)b * 4096 * 512;
#pragma unroll
  for (int i = 0; i < 4; i++) {
    int n = ty + i * 8;
    dst[ob + (size_t)(n0 + n) * 512 + c0 + tx] = (bf16)tile[tx][n];
  }
}

// ------------- Kernel 2: generic GEMM  out[r,co] = sum_k A[r,k]*W[co,k] + bias[co] -------------
// MODE 0: out bf16 [B,4096,512]   (Q, K)
// MODE 1: out bf16 transposed [B,512,4096]  (V -> Vt)
// MODE 2: out fp32 transposed [B,512,4096] + residual feat0  (final)
template<int MODE>
__global__ __launch_bounds__(256) void gemm_k(const bf16* __restrict__ A, const bf16* __restrict__ W,
                                              const float* __restrict__ bias, bf16* __restrict__ outB,
                                              float* __restrict__ outF, const float* __restrict__ resid) {
  const int b = blockIdx.y;
  const int rt = blockIdx.x >> 2, ct = blockIdx.x & 3;
  const int r0 = rt * 128, c0 = ct * 128;
  const int t = threadIdx.x, w = t >> 6, l = t & 63;
  __shared__ alignas(16) bf16 As[128 * 32];
  __shared__ alignas(16) bf16 Bs[128 * 32];
  f32x4 acc[4][4];
  const f32x4 fzero = {0.f, 0.f, 0.f, 0.f};
#pragma unroll
  for (int m = 0; m < 4; m++)
#pragma unroll
    for (int n = 0; n < 4; n++) acc[m][n] = fzero;
  const bf16* Ab = A + (size_t)b * 4096 * 512 + (size_t)r0 * 512;
  const int wr = (w >> 1) * 64, wc = (w & 1) * 64;
  for (int kk = 0; kk < 16; kk++) {
    const int k0 = kk * 32;
#pragma unroll
    for (int h = 0; h < 2; h++) {
      const int rowbase = w * 32 + h * 16;
      const int row = rowbase + (l >> 2);
      const int cl = (l & 3) ^ ((row >> 1) & 3);
      gll16(Ab + (size_t)row * 512 + k0 + cl * 8, As + rowbase * 32);
      gll16(W + (size_t)(c0 + row) * 512 + k0 + cl * 8, Bs + rowbase * 32);
    }
    __syncthreads();
    bf16x8 af[4], bfr[4];
#pragma unroll
    for (int m = 0; m < 4; m++) {
      const int row = wr + m * 16 + (l & 15);
      af[m] = *(const bf16x8*)(As + row * 32 + (((l >> 4) ^ ((row >> 1) & 3)) << 3));
    }
#pragma unroll
    for (int n = 0; n < 4; n++) {
      const int row = wc + n * 16 + (l & 15);
      bfr[n] = *(const bf16x8*)(Bs + row * 32 + (((l >> 4) ^ ((row >> 1) & 3)) << 3));
    }
#pragma unroll
    for (int m = 0; m < 4; m++)
#pragma unroll
      for (int n = 0; n < 4; n++)
        acc[m][n] = MFMA16(af[m], bfr[n], acc[m][n]);
    __syncthreads();
  }
#pragma unroll
  for (int n = 0; n < 4; n++) {
    const int co = c0 + wc + n * 16 + (l & 15);
    const float bv = bias[co];
#pragma unroll
    for (int m = 0; m < 4; m++) {
      const int rb = r0 + wr + m * 16 + ((l >> 4) << 2);
      if constexpr (MODE == 0) {
#pragma unroll
        for (int i = 0; i < 4; i++)
          outB[(size_t)b * 4096 * 512 + (size_t)(rb + i) * 512 + co] = (bf16)(acc[m][n][i] + bv);
      } else if constexpr (MODE == 1) {
        bf16x4v pk;
#pragma unroll
        for (int i = 0; i < 4; i++) pk[i] = (bf16)(acc[m][n][i] + bv);
        *(bf16x4v*)(outB + ((size_t)b * 512 + co) * 4096 + rb) = pk;
      } else {
        const size_t o = ((size_t)b * 512 + co) * 4096 + rb;
        float4 rv = *(const float4*)(resid + o);
        float4 ov;
        ov.x = acc[m][n][0] + bv + rv.x;
        ov.y = acc[m][n][1] + bv + rv.y;
        ov.z = acc[m][n][2] + bv + rv.z;
        ov.w = acc[m][n][3] + bv + rv.w;
        *(float4*)(outF + o) = ov;
      }
    }
  }
}

// ------------- Kernel 3: flash cross-attention -------------
// Q [B,4096,512] bf16, K [B,4096,512] bf16, Vt [B,512,4096] bf16 -> ctx [B,4096,512] bf16
// ctx = (softmax(QK^T) * C^-0.5) @ V
__global__ __launch_bounds__(256, 1) void flash_k(const bf16* __restrict__ Q, const bf16* __restrict__ K,
                                                  const bf16* __restrict__ Vt, bf16* __restrict__ ctx) {
  const int b = blockIdx.y;
  const int n0 = blockIdx.x * 64;
  const int t = threadIdx.x, w = t >> 6, l = t & 63;
  __shared__ alignas(16) bf16 Ks[32 * 512];   // rows=m-local(32), 1KB/row, chunk^(row&7) swizzle
  __shared__ alignas(16) bf16 Vs[512 * 32];   // rows=co(512), 64B/row, chunk^((row>>1)&3) swizzle
  __shared__ alignas(16) bf16 Ps[4 * 16 * 32]; // per-wave P tile
  bf16x8 qf[16];
  {
    const bf16* Qb = Q + ((size_t)b * 4096 + n0 + w * 16 + (l & 15)) * 512 + ((l >> 4) << 3);
#pragma unroll
    for (int f = 0; f < 16; f++) qf[f] = *(const bf16x8*)(Qb + f * 32);
  }
  f32x4 acc[32];
  const f32x4 fzero = {0.f, 0.f, 0.f, 0.f};
#pragma unroll
  for (int f = 0; f < 32; f++) acc[f] = fzero;
  float mrow[4], lrow[4];
#pragma unroll
  for (int i = 0; i < 4; i++) { mrow[i] = -1e30f; lrow[i] = 0.f; }
  const size_t kb = (size_t)b * 4096 * 512;
  const size_t vb = (size_t)b * 512 * 4096;
  bf16* Pw = Ps + w * 512;

  for (int mt = 0; mt < 128; ++mt) {
    const int m0 = mt * 32;
    // stage K tile rows (this wave: rows w*8 .. w*8+7), source-swizzled for bank-free reads
#pragma unroll
    for (int rr = 0; rr < 8; rr++) {
      const int row = w * 8 + rr;
      const int cl = l ^ (row & 7);
      gll16(K + kb + (size_t)(m0 + row) * 512 + cl * 8, Ks + row * 512);
    }
    // stage Vt tile: 2048 16B-chunks over 256 threads
#pragma unroll
    for (int pp = 0; pp < 8; pp++) {
      const int q = pp * 256 + t;
      const int co = q >> 2, ch = q & 3;
      const int cl = ch ^ ((co >> 1) & 3);
      ((uint4*)Vs)[q] = *(const uint4*)(Vt + vb + (size_t)co * 4096 + m0 + cl * 8);
    }
    __syncthreads();
    // S = Q K^T for this wave's 16 rows x 32 cols
    f32x4 s0 = fzero, s1 = fzero;
    const int rA = (l & 15), rB = rA + 16;
#pragma unroll
    for (int f2 = 0; f2 < 16; ++f2) {
      const int lc = (f2 << 2) + (l >> 4);
      bf16x8 k0 = *(const bf16x8*)(Ks + rA * 512 + ((lc ^ (rA & 7)) << 3));
      bf16x8 k1 = *(const bf16x8*)(Ks + rB * 512 + ((lc ^ (rB & 7)) << 3));
      s0 = MFMA16(qf[f2], k0, s0);
      s1 = MFMA16(qf[f2], k1, s1);
    }
    // online softmax (rows owned per-lane: row=(l>>4)*4+i, reduce over 16 lanes)
    f32x4 scv;
#pragma unroll
    for (int i = 0; i < 4; i++) {
      float a = s0[i], c2 = s1[i];
      float mx = fmaxf(a, c2);
      mx = fmaxf(mx, __shfl_xor(mx, 1));
      mx = fmaxf(mx, __shfl_xor(mx, 2));
      mx = fmaxf(mx, __shfl_xor(mx, 4));
      mx = fmaxf(mx, __shfl_xor(mx, 8));
      const float nm = fmaxf(mrow[i], mx);
      const float sc = __expf(mrow[i] - nm);
      const float p0 = __expf(a - nm), p1 = __expf(c2 - nm);
      float rs = p0 + p1;
      rs += __shfl_xor(rs, 1);
      rs += __shfl_xor(rs, 2);
      rs += __shfl_xor(rs, 4);
      rs += __shfl_xor(rs, 8);
      lrow[i] = lrow[i] * sc + rs;
      mrow[i] = nm;
      scv[i] = sc;
      const int prow = ((l >> 4) << 2) + i;
      const int sw = (prow >> 1) & 3;
      const int mA = l & 15, mB2 = mA + 16;
      Pw[prow * 32 + (((mA >> 3) ^ sw) << 3) + (mA & 7)] = (bf16)p0;
      Pw[prow * 32 + (((mB2 >> 3) ^ sw) << 3) + (mB2 & 7)] = (bf16)p1;
    }
#pragma unroll
    for (int f = 0; f < 32; f++) acc[f] *= scv;
    asm volatile("s_waitcnt lgkmcnt(0)" ::: "memory");
    __builtin_amdgcn_sched_barrier(0);
    // PV: ctx += P @ V  (A = P from wave-private LDS, B = Vt rows)
    {
      const int pr = l & 15;
      bf16x8 pf = *(const bf16x8*)(Pw + pr * 32 + (((l >> 4) ^ ((pr >> 1) & 3)) << 3));
#pragma unroll
      for (int f = 0; f < 32; f++) {
        const int co = (f << 4) + (l & 15);
        bf16x8 vf = *(const bf16x8*)(Vs + co * 32 + (((l >> 4) ^ ((co >> 1) & 3)) << 3));
        acc[f] = MFMA16(pf, vf, acc[f]);
      }
    }
    __syncthreads();
  }
  // epilogue: ctx = acc / l * C^-0.5
  f32x4 fin;
#pragma unroll
  for (int i = 0; i < 4; i++) fin[i] = 0.04419417382415922f / lrow[i];
  const size_t ob = (size_t)b * 4096 * 512;
#pragma unroll
  for (int f = 0; f < 32; f++) {
    const int c = (f << 4) + (l & 15);
#pragma unroll
    for (int i = 0; i < 4; i++) {
      const int n = n0 + w * 16 + ((l >> 4) << 2) + i;
      ctx[ob + (size_t)n * 512 + c] = (bf16)(acc[f][i] * fin[i]);
    }
  }
}

extern "C" void kernel_launch(void* const* d_in, const int* in_sizes, int n_in,
                              void* d_out, int out_size, void* d_ws, size_t ws_size,
                              hipStream_t stream) {
  const float* feat0 = (const float*)d_in[0];
  const float* feat1 = (const float*)d_in[1];
  const float* Wq = (const float*)d_in[2];
  const float* bq = (const float*)d_in[3];
  const float* Wk = (const float*)d_in[4];
  const float* bk = (const float*)d_in[5];
  const float* Wv = (const float*)d_in[6];
  const float* bv = (const float*)d_in[7];
  const float* Wo = (const float*)d_in[8];
  const float* bo = (const float*)d_in[9];
  float* out = (float*)d_out;

  char* ws = (char*)d_ws;
  bf16* Wqb = (bf16*)(ws);
  bf16* Wkb = (bf16*)(ws + (1 << 19));
  bf16* Wvb = (bf16*)(ws + 2 * (size_t)(1 << 19));
  bf16* Wob = (bf16*)(ws + 3 * (size_t)(1 << 19));
  const size_t TEN = (size_t)8 * 4096 * 512 * 2;  // 33.55 MB per bf16 tensor
  char* p = ws + 4 * (size_t)(1 << 19);
  bf16* Xq  = (bf16*)(p);
  bf16* Xkv = (bf16*)(p + TEN);
  bf16* Qb  = (bf16*)(p + 2 * TEN);
  bf16* Kb  = (bf16*)(p + 3 * TEN);
  bf16* Vtb = (bf16*)(p + 4 * TEN);
  bf16* ctx = Xq;  // Xq dead after Q projection

  convw_k<<<256, 256, 0, stream>>>(Wq, Wqb);
  convw_k<<<256, 256, 0, stream>>>(Wk, Wkb);
  convw_k<<<256, 256, 0, stream>>>(Wv, Wvb);
  convw_k<<<256, 256, 0, stream>>>(Wo, Wob);
  tconv_k<<<dim3(128, 16, 16), dim3(32, 8), 0, stream>>>(feat0, feat1, Xq, Xkv);
  gemm_k<0><<<dim3(128, 8), 256, 0, stream>>>(Xq,  Wqb, bq, Qb,  nullptr, nullptr);
  gemm_k<0><<<dim3(128, 8), 256, 0, stream>>>(Xkv, Wkb, bk, Kb,  nullptr, nullptr);
  gemm_k<1><<<dim3(128, 8), 256, 0, stream>>>(Xkv, Wvb, bv, Vtb, nullptr, nullptr);
  flash_k<<<dim3(64, 8), 256, 0, stream>>>(Qb, Kb, Vtb, ctx);
  gemm_k<2><<<dim3(128, 8), 256, 0, stream>>>(ctx, Wob, bo, nullptr, out, feat0);
}

// Round 2
// 633.486 us; speedup vs baseline: 2.0328x; 2.0328x over previous
//
#include <hip/hip_runtime.h>

#define AS1 __attribute__((address_space(1)))
#define AS3 __attribute__((address_space(3)))

typedef __bf16 bf16;
typedef __bf16 bf16x8 __attribute__((ext_vector_type(8)));
typedef __bf16 bf16x4v __attribute__((ext_vector_type(4)));
typedef float  f32x4  __attribute__((ext_vector_type(4)));

#define MFMA16(a,b,c) __builtin_amdgcn_mfma_f32_16x16x32_bf16((a),(b),(c),0,0,0)

static __device__ __forceinline__ void gll16(const bf16* src, bf16* lds) {
  __builtin_amdgcn_global_load_lds((const AS1 void*)src, (AS3 void*)lds, 16, 0, 0);
}

// ---------------- Kernel 0: weights fp32 -> bf16 ----------------
__global__ void convw_k(const float* __restrict__ s, bf16* __restrict__ d) {
  int i = (blockIdx.x * 256 + threadIdx.x) * 4;
  float4 v = *(const float4*)(s + i);
  bf16x4v o;
  o[0] = (bf16)v.x; o[1] = (bf16)v.y; o[2] = (bf16)v.z; o[3] = (bf16)v.w;
  *(bf16x4v*)(d + i) = o;
}

// ------------- Kernel 1: transpose+convert feat [B,C,4096] -> [B,4096,C] bf16 -------------
__global__ void tconv_k(const float* __restrict__ f0, const float* __restrict__ f1,
                        bf16* __restrict__ xq, bf16* __restrict__ xkv) {
  const int z = blockIdx.z;
  const int b = z & 7;
  const float* src = (z < 8) ? f0 : f1;
  bf16* dst = (z < 8) ? xq : xkv;
  const int n0 = blockIdx.x * 32, c0 = blockIdx.y * 32;
  __shared__ float tile[32][33];
  const int tx = threadIdx.x, ty = threadIdx.y;
  const size_t base = (size_t)b * 512 * 4096;
#pragma unroll
  for (int i = 0; i < 4; i++) {
    int c = ty + i * 8;
    tile[c][tx] = src[base + (size_t)(c0 + c) * 4096 + n0 + tx];
  }
  __syncthreads();
  const size_t ob = (size_t)b * 4096 * 512;
#pragma unroll
  for (int i = 0; i < 4; i++) {
    int n = ty + i * 8;
    dst[ob + (size_t)(n0 + n) * 512 + c0 + tx] = (bf16)tile[tx][n];
  }
}

// ------------- Kernel 2: generic GEMM  out[r,co] = sum_k A[r,k]*W[co,k] + bias[co] -------------
// MODE 0: out bf16 [B,4096,512]   (Q, K)
// MODE 1: out bf16 block-tiled [B][kblk=128][co=512][ki=32]  (V -> Vt tiled)
// MODE 2: out fp32 transposed [B,512,4096] + residual feat0  (final)
template<int MODE>
__global__ __launch_bounds__(256) void gemm_k(const bf16* __restrict__ A, const bf16* __restrict__ W,
                                              const float* __restrict__ bias, bf16* __restrict__ outB,
                                              float* __restrict__ outF, const float* __restrict__ resid) {
  const int b = blockIdx.y;
  const int rt = blockIdx.x >> 2, ct = blockIdx.x & 3;
  const int r0 = rt * 128, c0 = ct * 128;
  const int t = threadIdx.x, w = t >> 6, l = t & 63;
  __shared__ alignas(16) bf16 As[128 * 32];
  __shared__ alignas(16) bf16 Bs[128 * 32];
  f32x4 acc[4][4];
  const f32x4 fzero = {0.f, 0.f, 0.f, 0.f};
#pragma unroll
  for (int m = 0; m < 4; m++)
#pragma unroll
    for (int n = 0; n < 4; n++) acc[m][n] = fzero;
  const bf16* Ab = A + (size_t)b * 4096 * 512 + (size_t)r0 * 512;
  const int wr = (w >> 1) * 64, wc = (w & 1) * 64;
  for (int kk = 0; kk < 16; kk++) {
    const int k0 = kk * 32;
#pragma unroll
    for (int h = 0; h < 2; h++) {
      const int rowbase = w * 32 + h * 16;
      const int row = rowbase + (l >> 2);
      const int cl = (l & 3) ^ ((row >> 1) & 3);
      gll16(Ab + (size_t)row * 512 + k0 + cl * 8, As + rowbase * 32);
      gll16(W + (size_t)(c0 + row) * 512 + k0 + cl * 8, Bs + rowbase * 32);
    }
    __syncthreads();
    bf16x8 af[4], bfr[4];
#pragma unroll
    for (int m = 0; m < 4; m++) {
      const int row = wr + m * 16 + (l & 15);
      af[m] = *(const bf16x8*)(As + row * 32 + (((l >> 4) ^ ((row >> 1) & 3)) << 3));
    }
#pragma unroll
    for (int n = 0; n < 4; n++) {
      const int row = wc + n * 16 + (l & 15);
      bfr[n] = *(const bf16x8*)(Bs + row * 32 + (((l >> 4) ^ ((row >> 1) & 3)) << 3));
    }
#pragma unroll
    for (int m = 0; m < 4; m++)
#pragma unroll
      for (int n = 0; n < 4; n++)
        acc[m][n] = MFMA16(af[m], bfr[n], acc[m][n]);
    __syncthreads();
  }
#pragma unroll
  for (int n = 0; n < 4; n++) {
    const int co = c0 + wc + n * 16 + (l & 15);
    const float bv = bias[co];
#pragma unroll
    for (int m = 0; m < 4; m++) {
      const int rb = r0 + wr + m * 16 + ((l >> 4) << 2);
      if constexpr (MODE == 0) {
#pragma unroll
        for (int i = 0; i < 4; i++)
          outB[(size_t)b * 4096 * 512 + (size_t)(rb + i) * 512 + co] = (bf16)(acc[m][n][i] + bv);
      } else if constexpr (MODE == 1) {
        bf16x4v pk;
#pragma unroll
        for (int i = 0; i < 4; i++) pk[i] = (bf16)(acc[m][n][i] + bv);
        const size_t o = (((size_t)b * 128 + (rb >> 5)) * 512 + co) * 32 + (rb & 31);
        *(bf16x4v*)(outB + o) = pk;
      } else {
        const size_t o = ((size_t)b * 512 + co) * 4096 + rb;
        float4 rv = *(const float4*)(resid + o);
        float4 ov;
        ov.x = acc[m][n][0] + bv + rv.x;
        ov.y = acc[m][n][1] + bv + rv.y;
        ov.z = acc[m][n][2] + bv + rv.z;
        ov.w = acc[m][n][3] + bv + rv.w;
        *(float4*)(outF + o) = ov;
      }
    }
  }
}

// ------------- Kernel 3: flash cross-attention (8 waves, 128 Q rows/block) -------------
// Q [B,4096,512] bf16; K [B,4096,512] bf16; Vt tiled [B][128][512][32] bf16 -> ctx [B,4096,512] bf16
// ctx = (softmax(QK^T) * C^-0.5) @ V ; swapped-QK so each lane owns one Q-row's scores.
__global__ __launch_bounds__(512, 2) void flash_k(const bf16* __restrict__ Q, const bf16* __restrict__ K,
                                                  const bf16* __restrict__ Vt, bf16* __restrict__ ctx) {
  __shared__ alignas(16) bf16 Ks[2][32 * 512];
  __shared__ alignas(16) bf16 Vs[2][512 * 32];
  const int flat = blockIdx.x;
  const int fs = (flat & 7) * 32 + (flat >> 3);       // XCD swizzle (256 = 8*32, bijective)
  const int b = fs >> 5, n0 = (fs & 31) * 128;
  const int t = threadIdx.x, w = t >> 6, l = t & 63;
  const int g = l >> 4, r = l & 15;

  // Q fragments (B-operand): lane holds Q[n0+w*16+r][f*32 + g*8 .. +7]
  bf16x8 qf[16];
  {
    const bf16* Qb = Q + ((size_t)b * 4096 + n0 + w * 16 + r) * 512 + g * 8;
#pragma unroll
    for (int f = 0; f < 16; f++) qf[f] = *(const bf16x8*)(Qb + f * 32);
  }
  // staging source offsets (per-thread, tile-invariant)
  int koff[4], voff[4];
#pragma unroll
  for (int rr = 0; rr < 4; rr++) {
    const int row = w * 4 + rr;
    koff[rr] = row * 512 + ((l ^ (row & 7)) << 3);
  }
#pragma unroll
  for (int i = 0; i < 4; i++) {
    const int q = i * 512 + t;
    const int co = q >> 2;
    voff[i] = co * 32 + (((q & 3) ^ ((co >> 1) & 3)) << 3);
  }
  const bf16* Kb = K + (size_t)b * 4096 * 512;
  const bf16* Vb = Vt + (size_t)b * 128 * 16384;

  f32x4 acc[32];
  const f32x4 fz = {0.f, 0.f, 0.f, 0.f};
#pragma unroll
  for (int f = 0; f < 32; f++) acc[f] = fz;
  float mrow = -1e30f, lrow = 0.f;

  // prologue: stage tile 0 into buf 0
#pragma unroll
  for (int rr = 0; rr < 4; rr++) gll16(Kb + koff[rr], &Ks[0][0] + (w * 4 + rr) * 512);
#pragma unroll
  for (int i = 0; i < 4; i++) gll16(Vb + voff[i], &Vs[0][0] + i * 4096 + w * 512);

  const int kswz = r & 7;
  int cur = 0;
  for (int mt = 0; mt < 128; ++mt) {
    if (mt + 1 < 128) {
      const bf16* ks = Kb + (size_t)(mt + 1) * 16384;
      const bf16* vs2 = Vb + (size_t)(mt + 1) * 16384;
      const int bo = (cur ^ 1) * 16384;
#pragma unroll
      for (int rr = 0; rr < 4; rr++) gll16(ks + koff[rr], &Ks[0][0] + bo + (w * 4 + rr) * 512);
#pragma unroll
      for (int i = 0; i < 4; i++) gll16(vs2 + voff[i], &Vs[0][0] + bo + i * 4096 + w * 512);
      asm volatile("s_waitcnt vmcnt(8)" ::: "memory");
    } else {
      asm volatile("s_waitcnt vmcnt(0)" ::: "memory");
    }
    __builtin_amdgcn_s_barrier();
    asm volatile("" ::: "memory");

    // ---- QK^T (swapped: S^T[key][qrow]); 4 independent MFMA chains ----
    const bf16* kb0 = &Ks[cur][0] + r * 512;
    f32x4 sa = fz, sb = fz, sc2 = fz, sd = fz;
#pragma unroll
    for (int f2 = 0; f2 < 16; f2 += 2) {
      const int c0i = ((((f2 << 2) + g) ^ kswz) << 3);
      const int c1i = (((((f2 + 1) << 2) + g) ^ kswz) << 3);
      bf16x8 k0 = *(const bf16x8*)(kb0 + c0i);
      bf16x8 k1 = *(const bf16x8*)(kb0 + 16 * 512 + c0i);
      bf16x8 k2 = *(const bf16x8*)(kb0 + c1i);
      bf16x8 k3 = *(const bf16x8*)(kb0 + 16 * 512 + c1i);
      sa = MFMA16(k0, qf[f2], sa);
      sb = MFMA16(k1, qf[f2], sb);
      sc2 = MFMA16(k2, qf[f2 + 1], sc2);
      sd = MFMA16(k3, qf[f2 + 1], sd);
    }
    const f32x4 s0 = sa + sc2, s1 = sb + sd;   // lane: row r, keys 4g+i / 16+4g+i

    // ---- online softmax, defer-max (THR=8) ----
    float pmax = fmaxf(fmaxf(fmaxf(s0[0], s0[1]), fmaxf(s0[2], s0[3])),
                       fmaxf(fmaxf(s1[0], s1[1]), fmaxf(s1[2], s1[3])));
    pmax = fmaxf(pmax, __shfl_xor(pmax, 16));
    pmax = fmaxf(pmax, __shfl_xor(pmax, 32));
    if (!__all(pmax <= mrow + 8.0f)) {
      const float mnew = fmaxf(mrow, pmax);
      const float scl = __expf(mrow - mnew);
      mrow = mnew;
      lrow *= scl;
      const int sclI = __float_as_int(scl);
      f32x4 sc4;
#pragma unroll
      for (int i = 0; i < 4; i++)
        sc4[i] = __int_as_float(__builtin_amdgcn_ds_bpermute(((g << 2) + i) << 2, sclI));
#pragma unroll
      for (int f = 0; f < 32; f++) acc[f] *= sc4;
    }
    float p0[4], p1[4];
#pragma unroll
    for (int i = 0; i < 4; i++) { p0[i] = __expf(s0[i] - mrow); p1[i] = __expf(s1[i] - mrow); }
    float rs = (p0[0] + p0[1]) + (p0[2] + p0[3]) + (p1[0] + p1[1]) + (p1[2] + p1[3]);
    rs += __shfl_xor(rs, 16);
    rs += __shfl_xor(rs, 32);
    lrow += rs;

    // ---- pack P->bf16, redistribute to PV A-fragment via bpermute ----
    uint ua, ub, uc, ud;
    asm("v_cvt_pk_bf16_f32 %0, %1, %2" : "=v"(ua) : "v"(p0[0]), "v"(p0[1]));
    asm("v_cvt_pk_bf16_f32 %0, %1, %2" : "=v"(ub) : "v"(p0[2]), "v"(p0[3]));
    asm("v_cvt_pk_bf16_f32 %0, %1, %2" : "=v"(uc) : "v"(p1[0]), "v"(p1[1]));
    asm("v_cvt_pk_bf16_f32 %0, %1, %2" : "=v"(ud) : "v"(p1[2]), "v"(p1[3]));
    const int l0 = (((((g << 1) & 3) << 4) + r) << 2);
    const int l1 = l0 + 64;
    const int A0 = __builtin_amdgcn_ds_bpermute(l0, (int)ua);
    const int B0 = __builtin_amdgcn_ds_bpermute(l0, (int)ub);
    const int A1 = __builtin_amdgcn_ds_bpermute(l1, (int)ua);
    const int B1 = __builtin_amdgcn_ds_bpermute(l1, (int)ub);
    const int C0 = __builtin_amdgcn_ds_bpermute(l0, (int)uc);
    const int D0 = __builtin_amdgcn_ds_bpermute(l0, (int)ud);
    const int C1 = __builtin_amdgcn_ds_bpermute(l1, (int)uc);
    const int D1 = __builtin_amdgcn_ds_bpermute(l1, (int)ud);
    union { int i4[4]; bf16x8 v; } pu;
    const bool lo = (g < 2);
    pu.i4[0] = lo ? A0 : C0;
    pu.i4[1] = lo ? B0 : D0;
    pu.i4[2] = lo ? A1 : C1;
    pu.i4[3] = lo ? B1 : D1;
    const bf16x8 pf = pu.v;

    // ---- PV: acc += P @ V ----
    const bf16* vb0 = &Vs[cur][0];
#pragma unroll
    for (int f = 0; f < 32; f++) {
      const int co = (f << 4) + r;
      bf16x8 vf = *(const bf16x8*)(vb0 + co * 32 + ((g ^ ((co >> 1) & 3)) << 3));
      acc[f] = MFMA16(pf, vf, acc[f]);
    }
    asm volatile("" ::: "memory");
    __builtin_amdgcn_s_barrier();
    cur ^= 1;
  }

  // epilogue: ctx = acc / l * C^-0.5  (pull each acc-row's denom from its owner lane)
  f32x4 fin;
#pragma unroll
  for (int i = 0; i < 4; i++) {
    const float li = __int_as_float(
        __builtin_amdgcn_ds_bpermute(((g << 2) + i) << 2, __float_as_int(lrow)));
    fin[i] = 0.04419417382415922f / li;
  }
  const size_t ob = (size_t)b * 4096 * 512;
#pragma unroll
  for (int f = 0; f < 32; f++) {
    const int c = (f << 4) + r;
#pragma unroll
    for (int i = 0; i < 4; i++) {
      const int n = n0 + w * 16 + (g << 2) + i;
      ctx[ob + (size_t)n * 512 + c] = (bf16)(acc[f][i] * fin[i]);
    }
  }
}

extern "C" void kernel_launch(void* const* d_in, const int* in_sizes, int n_in,
                              void* d_out, int out_size, void* d_ws, size_t ws_size,
                              hipStream_t stream) {
  const float* feat0 = (const float*)d_in[0];
  const float* feat1 = (const float*)d_in[1];
  const float* Wq = (const float*)d_in[2];
  const float* bq = (const float*)d_in[3];
  const float* Wk = (const float*)d_in[4];
  const float* bk = (const float*)d_in[5];
  const float* Wv = (const float*)d_in[6];
  const float* bv = (const float*)d_in[7];
  const float* Wo = (const float*)d_in[8];
  const float* bo = (const float*)d_in[9];
  float* out = (float*)d_out;

  char* ws = (char*)d_ws;
  bf16* Wqb = (bf16*)(ws);
  bf16* Wkb = (bf16*)(ws + (1 << 19));
  bf16* Wvb = (bf16*)(ws + 2 * (size_t)(1 << 19));
  bf16* Wob = (bf16*)(ws + 3 * (size_t)(1 << 19));
  const size_t TEN = (size_t)8 * 4096 * 512 * 2;  // 33.55 MB per bf16 tensor
  char* p = ws + 4 * (size_t)(1 << 19);
  bf16* Xq  = (bf16*)(p);
  bf16* Xkv = (bf16*)(p + TEN);
  bf16* Qb  = (bf16*)(p + 2 * TEN);
  bf16* Kb  = (bf16*)(p + 3 * TEN);
  bf16* Vtb = (bf16*)(p + 4 * TEN);
  bf16* ctx = Xq;  // Xq dead after Q projection

  convw_k<<<256, 256, 0, stream>>>(Wq, Wqb);
  convw_k<<<256, 256, 0, stream>>>(Wk, Wkb);
  convw_k<<<256, 256, 0, stream>>>(Wv, Wvb);
  convw_k<<<256, 256, 0, stream>>>(Wo, Wob);
  tconv_k<<<dim3(128, 16, 16), dim3(32, 8), 0, stream>>>(feat0, feat1, Xq, Xkv);
  gemm_k<0><<<dim3(128, 8), 256, 0, stream>>>(Xq,  Wqb, bq, Qb,  nullptr, nullptr);
  gemm_k<0><<<dim3(128, 8), 256, 0, stream>>>(Xkv, Wkb, bk, Kb,  nullptr, nullptr);
  gemm_k<1><<<dim3(128, 8), 256, 0, stream>>>(Xkv, Wvb, bv, Vtb, nullptr, nullptr);
  flash_k<<<dim3(256), dim3(512), 0, stream>>>(Qb, Kb, Vtb, ctx);
  gemm_k<2><<<dim3(128, 8), 256, 0, stream>>>(ctx, Wob, bo, nullptr, out, feat0);
}